// Round 14
// baseline (480.780 us; speedup 1.0000x reference)
//
#include <hip/hip_runtime.h>
#include <hip/hip_bf16.h>
#include <math.h>

typedef short short8 __attribute__((ext_vector_type(8)));
typedef short s4v __attribute__((ext_vector_type(4)));
typedef float f32x4 __attribute__((ext_vector_type(4)));
typedef unsigned short ushort4v __attribute__((ext_vector_type(4)));

#define T_TOK 4096
#define D_DIM 1024
#define E_NUM 8
#define F_DIM 4096
#define NSLOT (2 * T_TOK)

#define BT 256      // tile (BM = BN = 256)
#define BKT 64      // K-tile
#define NTH 512     // 8 waves: 2 (M) x 4 (N)
#define GROWS 5     // row tiles of 256 (covers count <= 1280 ≈ mean + 8.5 sigma)
#define KSPL 2      // gemm2 split-K

__device__ __forceinline__ short f2bf(float f) {
  unsigned u = __builtin_bit_cast(unsigned, f);
  u = (u + 0x7FFFu + ((u >> 16) & 1u)) >> 16;
  return (short)u;
}
__device__ __forceinline__ float bf2f(unsigned short s) {
  unsigned u = ((unsigned)s) << 16;
  return __builtin_bit_cast(float, u);
}

__device__ __forceinline__ void gload_lds16(unsigned short* lds, const unsigned short* g) {
  __builtin_amdgcn_global_load_lds(
      (const __attribute__((address_space(1))) unsigned int*)g,
      (__attribute__((address_space(3))) unsigned int*)lds, 16, 0, 0);
}

#define MFMA_BF16 __builtin_amdgcn_mfma_f32_16x16x32_bf16

// ---------------- Router: fp64 gates + top-2; also emits x in bf16 ----------------
__global__ __launch_bounds__(64) void router_kernel(
    const float* __restrict__ x, const float* __restrict__ Wg,
    const float* __restrict__ bg,
    int* __restrict__ texp, float* __restrict__ tgate, int* __restrict__ cnt,
    unsigned short* __restrict__ xb) {
  int t = blockIdx.x;
  int lane = threadIdx.x;
  double acc[E_NUM];
#pragma unroll
  for (int e = 0; e < E_NUM; ++e) acc[e] = 0.0;
  const float* xr = x + (size_t)t * D_DIM;
  unsigned short* xbr = xb + (size_t)t * D_DIM;
  for (int d = lane; d < D_DIM; d += 64) {
    float xf = xr[d];
    xbr[d] = (unsigned short)f2bf(xf);
    double xv = (double)xf;
#pragma unroll
    for (int e = 0; e < E_NUM; ++e) acc[e] += xv * (double)Wg[d * E_NUM + e];
  }
#pragma unroll
  for (int off = 32; off > 0; off >>= 1) {
#pragma unroll
    for (int e = 0; e < E_NUM; ++e) acc[e] += __shfl_down(acc[e], off);
  }
  if (lane == 0) {
    double lg[E_NUM];
    double m = -1e300;
#pragma unroll
    for (int e = 0; e < E_NUM; ++e) {
      lg[e] = acc[e] + (double)bg[e];
      m = fmax(m, lg[e]);
    }
    double s = 0.0;
#pragma unroll
    for (int e = 0; e < E_NUM; ++e) { lg[e] = exp(lg[e] - m); s += lg[e]; }
    int e0 = 0; double g0 = lg[0];
#pragma unroll
    for (int e = 1; e < E_NUM; ++e) if (lg[e] > g0) { g0 = lg[e]; e0 = e; }
    int e1 = -1; double g1 = -1.0;
#pragma unroll
    for (int e = 0; e < E_NUM; ++e)
      if (e != e0 && lg[e] > g1) { g1 = lg[e]; e1 = e; }
    texp[2 * t]     = e0;
    texp[2 * t + 1] = e1;
    tgate[2 * t]     = (float)(g0 / s);
    tgate[2 * t + 1] = (float)(g1 / s);
    atomicAdd(&cnt[e0], 1);
    atomicAdd(&cnt[e1], 1);
  }
}

__global__ void offsets_kernel(const int* __restrict__ cnt,
                               int* __restrict__ off, int* __restrict__ cur) {
  if (threadIdx.x == 0 && blockIdx.x == 0) {
    int o = 0;
    for (int e = 0; e < E_NUM; ++e) { off[e] = o; cur[e] = o; o += cnt[e]; }
    off[E_NUM] = o;
  }
}

__global__ __launch_bounds__(256) void assign_kernel(
    const int* __restrict__ texp, const float* __restrict__ tgate,
    int* __restrict__ cur, int* __restrict__ tok_of, float* __restrict__ gate_of,
    int* __restrict__ slot_of) {
  int t = blockIdx.x * 256 + threadIdx.x;
  if (t >= T_TOK) return;
#pragma unroll
  for (int k = 0; k < 2; ++k) {
    int e = texp[2 * t + k];
    int s = atomicAdd(&cur[e], 1);
    tok_of[s] = t;
    gate_of[s] = tgate[2 * t + k];
    slot_of[2 * t + k] = s;
  }
}

// ---------------- per-expert [R][C] fp32 -> [C][R] bf16 ----------------
__global__ __launch_bounds__(256) void tconv_kernel(
    const float* __restrict__ in, unsigned short* __restrict__ out, int R, int C) {
  __shared__ float tile[64][65];
  int e = blockIdx.z;
  const float* ine = in + (size_t)e * R * C;
  unsigned short* oute = out + (size_t)e * R * C;
  int c0 = blockIdx.x * 64, r0 = blockIdx.y * 64;
  int tid = threadIdx.x;
  int lr = tid >> 4;
  int lc = (tid & 15) * 4;
#pragma unroll
  for (int p = 0; p < 4; ++p) {
    int row = p * 16 + lr;
    float4 v = *(const float4*)&ine[(size_t)(r0 + row) * C + c0 + lc];
    tile[row][lc] = v.x; tile[row][lc + 1] = v.y;
    tile[row][lc + 2] = v.z; tile[row][lc + 3] = v.w;
  }
  __syncthreads();
#pragma unroll
  for (int p = 0; p < 4; ++p) {
    int crow = p * 16 + lr;
    s4v o;
#pragma unroll
    for (int j = 0; j < 4; ++j) o[j] = f2bf(tile[lc + j][crow]);
    *(s4v*)&oute[(size_t)(c0 + crow) * R + r0 + lc] = o;
  }
}

// ============ 256x256 tile, BK=64, 512 thr (8 waves 2Mx4N), 128 KB LDS, counted vmcnt ============
// LDS rows of 64 bf16 (128B) = 8 granules of 16B; phys granule = logical ^ (row&7).
// gload dest linear (pos = i*512+tid granules); global source pre-swizzled.
// Loop: [vmcnt(8); barrier] 4 phases {frag reads; setprio; 16 MFMA; setprio; barrier} then stage t+2.

// ---------------- Grouped GEMM1: h = relu(xb @ W1^T + b1), bf16 ----------------
// 1D grid XCD-pinned: bid = e + 8*(fx + 16*ty)
__global__ __launch_bounds__(NTH, 2) void gemm1_kernel(
    const unsigned short* __restrict__ xb, const unsigned short* __restrict__ w1t,
    const float* __restrict__ b1,
    const int* __restrict__ off, const int* __restrict__ cnt,
    const int* __restrict__ tok_of, unsigned short* __restrict__ h) {
  int bid = blockIdx.x;
  int e = bid & 7;
  int w = bid >> 3;
  int fx = w & 15;
  int ty = w >> 4;
  int count = cnt[e];
  if (ty * BT >= count) return;
  int f0 = fx * BT;
  int base = off[e] + ty * BT;

  __shared__ __align__(16) unsigned short As[2][BT * BKT];  // 2 x 32 KB
  __shared__ __align__(16) unsigned short Bs[2][BT * BKT];  // 2 x 32 KB

  int tid = threadIdx.x;
  int lane = tid & 63;
  int wid = tid >> 6;
  int wr = wid >> 2, wc = wid & 3;   // wave tile 128 x 64

  const unsigned short* aga[4];
  const unsigned short* bga[4];
  const unsigned short* w1e = w1t + (size_t)e * ((size_t)F_DIM * D_DIM);
#pragma unroll
  for (int i = 0; i < 4; ++i) {
    int pos = i * NTH + tid;           // 2048 granules
    int row = pos >> 3;
    int sl = (pos & 7) ^ (row & 7);
    int idx = ty * BT + row;
    int tok = tok_of[(idx < count) ? (base + row) : off[e]];
    aga[i] = xb + (size_t)tok * D_DIM + sl * 8;
    bga[i] = w1e + (size_t)(f0 + row) * D_DIM + sl * 8;
  }

  f32x4 acc[8][4];
#pragma unroll
  for (int m = 0; m < 8; ++m)
#pragma unroll
    for (int n = 0; n < 4; ++n) acc[m][n] = (f32x4){0.f, 0.f, 0.f, 0.f};

#define STAGE1(buf, k0) do { \
    _Pragma("unroll") \
    for (int i = 0; i < 4; ++i) { \
      gload_lds16(&As[buf][(i * NTH + tid) * 8], aga[i] + (k0)); \
      gload_lds16(&Bs[buf][(i * NTH + tid) * 8], bga[i] + (k0)); \
    } \
  } while (0)

  STAGE1(0, 0);
  STAGE1(1, BKT);

  int rr = lane & 15, hi = lane >> 4;
  int soA0 = ((0 * 4 + hi) ^ (rr & 7)) * 8;   // kk=0 phys elem offset
  int soA1 = ((1 * 4 + hi) ^ (rr & 7)) * 8;   // kk=1
  const int nt = D_DIM / BKT;                 // 16
  for (int t = 0; t < nt; ++t) {
    if (t + 1 < nt) { asm volatile("s_waitcnt vmcnt(8)" ::: "memory"); }
    else            { asm volatile("s_waitcnt vmcnt(0)" ::: "memory"); }
    __builtin_amdgcn_s_barrier();
    __builtin_amdgcn_sched_barrier(0);

    const unsigned short* ab = &As[t & 1][0];
    const unsigned short* bb = &Bs[t & 1][0];
    short8 af[8], bf[4];

    // ---- phase 0: kk=0, n 0..1 ----
#pragma unroll
    for (int m = 0; m < 8; ++m)
      af[m] = *(const short8*)(ab + (wr * 128 + m * 16 + rr) * 64 + soA0);
#pragma unroll
    for (int n = 0; n < 2; ++n)
      bf[n] = *(const short8*)(bb + (wc * 64 + n * 16 + rr) * 64 + soA0);
    __builtin_amdgcn_s_setprio(1);
#pragma unroll
    for (int m = 0; m < 8; ++m) {
      acc[m][0] = MFMA_BF16(af[m], bf[0], acc[m][0], 0, 0, 0);
      acc[m][1] = MFMA_BF16(af[m], bf[1], acc[m][1], 0, 0, 0);
    }
    __builtin_amdgcn_s_setprio(0);
    __builtin_amdgcn_s_barrier();
    // ---- phase 1: kk=0, n 2..3 ----
#pragma unroll
    for (int n = 2; n < 4; ++n)
      bf[n] = *(const short8*)(bb + (wc * 64 + n * 16 + rr) * 64 + soA0);
    __builtin_amdgcn_s_setprio(1);
#pragma unroll
    for (int m = 0; m < 8; ++m) {
      acc[m][2] = MFMA_BF16(af[m], bf[2], acc[m][2], 0, 0, 0);
      acc[m][3] = MFMA_BF16(af[m], bf[3], acc[m][3], 0, 0, 0);
    }
    __builtin_amdgcn_s_setprio(0);
    __builtin_amdgcn_s_barrier();
    // ---- phase 2: kk=1, n 0..1 ----
#pragma unroll
    for (int m = 0; m < 8; ++m)
      af[m] = *(const short8*)(ab + (wr * 128 + m * 16 + rr) * 64 + soA1);
#pragma unroll
    for (int n = 0; n < 2; ++n)
      bf[n] = *(const short8*)(bb + (wc * 64 + n * 16 + rr) * 64 + soA1);
    __builtin_amdgcn_s_setprio(1);
#pragma unroll
    for (int m = 0; m < 8; ++m) {
      acc[m][0] = MFMA_BF16(af[m], bf[0], acc[m][0], 0, 0, 0);
      acc[m][1] = MFMA_BF16(af[m], bf[1], acc[m][1], 0, 0, 0);
    }
    __builtin_amdgcn_s_setprio(0);
    __builtin_amdgcn_s_barrier();
    // ---- phase 3: kk=1, n 2..3 ----
#pragma unroll
    for (int n = 2; n < 4; ++n)
      bf[n] = *(const short8*)(bb + (wc * 64 + n * 16 + rr) * 64 + soA1);
    __builtin_amdgcn_s_setprio(1);
#pragma unroll
    for (int m = 0; m < 8; ++m) {
      acc[m][2] = MFMA_BF16(af[m], bf[2], acc[m][2], 0, 0, 0);
      acc[m][3] = MFMA_BF16(af[m], bf[3], acc[m][3], 0, 0, 0);
    }
    __builtin_amdgcn_s_setprio(0);
    asm volatile("" ::: "memory");
    __builtin_amdgcn_s_barrier();   // all reads of buffer (t&1) complete
    asm volatile("" ::: "memory");
    if (t + 2 < nt) STAGE1(t & 1, (t + 2) * BKT);
  }
#undef STAGE1

  int col = lane & 15, rowq = (lane >> 4) * 4;
  float bias[4];
#pragma unroll
  for (int n = 0; n < 4; ++n) bias[n] = b1[e * F_DIM + f0 + wc * 64 + n * 16 + col];
#pragma unroll
  for (int m = 0; m < 8; ++m)
#pragma unroll
    for (int i = 0; i < 4; ++i) {
      int rl = wr * 128 + m * 16 + rowq + i;
      if (ty * BT + rl < count) {
        int slot = base + rl;
#pragma unroll
        for (int n = 0; n < 4; ++n) {
          int f = f0 + wc * 64 + n * 16 + col;
          float v = acc[m][n][i] + bias[n];
          h[(size_t)slot * F_DIM + f] = (unsigned short)f2bf(fmaxf(v, 0.f));
        }
      }
    }
}

// ---------------- Grouped GEMM2 (split-K=2, contention-free): yp[kc][slot][D] bf16 ----------------
// 1D grid XCD-pinned: bid = e + 8*(kc + 2*(cx + 4*ty))
__global__ __launch_bounds__(NTH, 2) void gemm2_kernel(
    const unsigned short* __restrict__ h, const unsigned short* __restrict__ w2t,
    const float* __restrict__ b2,
    const int* __restrict__ off, const int* __restrict__ cnt,
    unsigned short* __restrict__ yp) {
  int bid = blockIdx.x;
  int e = bid & 7;
  int w = bid >> 3;
  int kc = w & 1;
  int u = w >> 1;
  int cx = u & 3;
  int ty = u >> 2;
  int count = cnt[e];
  if (ty * BT >= count) return;
  int d0 = cx * BT;
  int klo = kc * (F_DIM / 2);
  int base = off[e] + ty * BT;

  __shared__ __align__(16) unsigned short As[2][BT * BKT];
  __shared__ __align__(16) unsigned short Bs[2][BT * BKT];

  int tid = threadIdx.x;
  int lane = tid & 63;
  int wid = tid >> 6;
  int wr = wid >> 2, wc = wid & 3;

  const unsigned short* aga[4];
  const unsigned short* bga[4];
  const unsigned short* w2e = w2t + (size_t)e * ((size_t)D_DIM * F_DIM);
#pragma unroll
  for (int i = 0; i < 4; ++i) {
    int pos = i * NTH + tid;
    int row = pos >> 3;
    int sl = (pos & 7) ^ (row & 7);
    int arow = base + row;
    if (arow > NSLOT - 1) arow = NSLOT - 1;
    aga[i] = h + (size_t)arow * F_DIM + klo + sl * 8;
    bga[i] = w2e + (size_t)(d0 + row) * F_DIM + klo + sl * 8;
  }

  f32x4 acc[8][4];
#pragma unroll
  for (int m = 0; m < 8; ++m)
#pragma unroll
    for (int n = 0; n < 4; ++n) acc[m][n] = (f32x4){0.f, 0.f, 0.f, 0.f};

#define STAGE2(buf, k0) do { \
    _Pragma("unroll") \
    for (int i = 0; i < 4; ++i) { \
      gload_lds16(&As[buf][(i * NTH + tid) * 8], aga[i] + (k0)); \
      gload_lds16(&Bs[buf][(i * NTH + tid) * 8], bga[i] + (k0)); \
    } \
  } while (0)

  STAGE2(0, 0);
  STAGE2(1, BKT);

  int rr = lane & 15, hi = lane >> 4;
  int soA0 = ((0 * 4 + hi) ^ (rr & 7)) * 8;
  int soA1 = ((1 * 4 + hi) ^ (rr & 7)) * 8;
  const int nt = (F_DIM / KSPL) / BKT;        // 32
  for (int t = 0; t < nt; ++t) {
    if (t + 1 < nt) { asm volatile("s_waitcnt vmcnt(8)" ::: "memory"); }
    else            { asm volatile("s_waitcnt vmcnt(0)" ::: "memory"); }
    __builtin_amdgcn_s_barrier();
    __builtin_amdgcn_sched_barrier(0);

    const unsigned short* ab = &As[t & 1][0];
    const unsigned short* bb = &Bs[t & 1][0];
    short8 af[8], bf[4];

#pragma unroll
    for (int m = 0; m < 8; ++m)
      af[m] = *(const short8*)(ab + (wr * 128 + m * 16 + rr) * 64 + soA0);
#pragma unroll
    for (int n = 0; n < 2; ++n)
      bf[n] = *(const short8*)(bb + (wc * 64 + n * 16 + rr) * 64 + soA0);
    __builtin_amdgcn_s_setprio(1);
#pragma unroll
    for (int m = 0; m < 8; ++m) {
      acc[m][0] = MFMA_BF16(af[m], bf[0], acc[m][0], 0, 0, 0);
      acc[m][1] = MFMA_BF16(af[m], bf[1], acc[m][1], 0, 0, 0);
    }
    __builtin_amdgcn_s_setprio(0);
    __builtin_amdgcn_s_barrier();
#pragma unroll
    for (int n = 2; n < 4; ++n)
      bf[n] = *(const short8*)(bb + (wc * 64 + n * 16 + rr) * 64 + soA0);
    __builtin_amdgcn_s_setprio(1);
#pragma unroll
    for (int m = 0; m < 8; ++m) {
      acc[m][2] = MFMA_BF16(af[m], bf[2], acc[m][2], 0, 0, 0);
      acc[m][3] = MFMA_BF16(af[m], bf[3], acc[m][3], 0, 0, 0);
    }
    __builtin_amdgcn_s_setprio(0);
    __builtin_amdgcn_s_barrier();
#pragma unroll
    for (int m = 0; m < 8; ++m)
      af[m] = *(const short8*)(ab + (wr * 128 + m * 16 + rr) * 64 + soA1);
#pragma unroll
    for (int n = 0; n < 2; ++n)
      bf[n] = *(const short8*)(bb + (wc * 64 + n * 16 + rr) * 64 + soA1);
    __builtin_amdgcn_s_setprio(1);
#pragma unroll
    for (int m = 0; m < 8; ++m) {
      acc[m][0] = MFMA_BF16(af[m], bf[0], acc[m][0], 0, 0, 0);
      acc[m][1] = MFMA_BF16(af[m], bf[1], acc[m][1], 0, 0, 0);
    }
    __builtin_amdgcn_s_setprio(0);
    __builtin_amdgcn_s_barrier();
#pragma unroll
    for (int n = 2; n < 4; ++n)
      bf[n] = *(const short8*)(bb + (wc * 64 + n * 16 + rr) * 64 + soA1);
    __builtin_amdgcn_s_setprio(1);
#pragma unroll
    for (int m = 0; m < 8; ++m) {
      acc[m][2] = MFMA_BF16(af[m], bf[2], acc[m][2], 0, 0, 0);
      acc[m][3] = MFMA_BF16(af[m], bf[3], acc[m][3], 0, 0, 0);
    }
    __builtin_amdgcn_s_setprio(0);
    asm volatile("" ::: "memory");
    __builtin_amdgcn_s_barrier();
    asm volatile("" ::: "memory");
    if (t + 2 < nt) STAGE2(t & 1, (t + 2) * BKT);
  }
#undef STAGE2

  int col = lane & 15, rowq = (lane >> 4) * 4;
  float bias[4];
#pragma unroll
  for (int n = 0; n < 4; ++n)
    bias[n] = (kc == 0) ? b2[e * D_DIM + d0 + wc * 64 + n * 16 + col] : 0.f;
  unsigned short* ypk = yp + (size_t)kc * NSLOT * D_DIM;
#pragma unroll
  for (int m = 0; m < 8; ++m)
#pragma unroll
    for (int i = 0; i < 4; ++i) {
      int rl = wr * 128 + m * 16 + rowq + i;
      if (ty * BT + rl < count) {
        int slot = base + rl;
#pragma unroll
        for (int n = 0; n < 4; ++n) {
          int d = d0 + wc * 64 + n * 16 + col;
          float v = acc[m][n][i] + bias[n];
          ypk[(size_t)slot * D_DIM + d] = (unsigned short)f2bf(v);
        }
      }
    }
}

// ---------------- Combine: out[t] = sum_k gate_k * sum_kc yp[kc][slot_k] ----------------
__global__ __launch_bounds__(256) void combine_kernel(
    const unsigned short* __restrict__ yp, const int* __restrict__ slot_of,
    const float* __restrict__ tgate, float* __restrict__ out) {
  int t = blockIdx.x;
  int d = threadIdx.x * 4;
  int s0 = slot_of[2 * t], s1 = slot_of[2 * t + 1];
  float g0 = tgate[2 * t], g1 = tgate[2 * t + 1];
  float4 o = {0.f, 0.f, 0.f, 0.f};
  float* op = (float*)&o;
#pragma unroll
  for (int kc = 0; kc < KSPL; ++kc) {
    const unsigned short* ypk = yp + (size_t)kc * NSLOT * D_DIM;
    ushort4v a = *(const ushort4v*)&ypk[(size_t)s0 * D_DIM + d];
    ushort4v b = *(const ushort4v*)&ypk[(size_t)s1 * D_DIM + d];
#pragma unroll
    for (int j = 0; j < 4; ++j)
      op[j] += g0 * bf2f(a[j]) + g1 * bf2f(b[j]);
  }
  *(float4*)&out[(size_t)t * D_DIM + d] = o;
}

extern "C" void kernel_launch(void* const* d_in, const int* in_sizes, int n_in,
                              void* d_out, int out_size, void* d_ws, size_t ws_size,
                              hipStream_t stream) {
  const float* x  = (const float*)d_in[0];
  const float* Wg = (const float*)d_in[1];
  const float* bg = (const float*)d_in[2];
  const float* W1 = (const float*)d_in[3];
  const float* b1 = (const float*)d_in[4];
  const float* W2 = (const float*)d_in[5];
  const float* b2 = (const float*)d_in[6];
  float* out = (float*)d_out;

  char* ws = (char*)d_ws;
  int*   cnt     = (int*)(ws + 0);
  int*   cur     = (int*)(ws + 256);
  int*   off     = (int*)(ws + 512);
  int*   texp    = (int*)(ws + 1024);
  float* tgate   = (float*)(ws + 1024 + NSLOT * 4);
  int*   tok_of  = (int*)(ws + 1024 + NSLOT * 8);
  float* gate_of = (float*)(ws + 1024 + NSLOT * 12);
  int*   slot_of = (int*)(ws + 1024 + NSLOT * 16);
  size_t o_xb   = 256 * 1024;
  size_t o_wt   = o_xb + (size_t)T_TOK * D_DIM * 2;                 // +8 MB
  size_t o_h    = o_wt + (size_t)E_NUM * D_DIM * F_DIM * 2;         // +64 MB
  size_t o_yp   = o_h + (size_t)NSLOT * F_DIM * 2;                  // +64 MB
  unsigned short* xb = (unsigned short*)(ws + o_xb);
  unsigned short* wt = (unsigned short*)(ws + o_wt);
  unsigned short* h  = (unsigned short*)(ws + o_h);
  unsigned short* yp = (unsigned short*)(ws + o_yp);                // 2 x 16 MB bf16

  hipMemsetAsync(ws, 0, 256, stream);

  router_kernel<<<T_TOK, 64, 0, stream>>>(x, Wg, bg, texp, tgate, cnt, xb);
  offsets_kernel<<<1, 64, 0, stream>>>(cnt, off, cur);
  assign_kernel<<<(T_TOK + 255) / 256, 256, 0, stream>>>(texp, tgate, cur, tok_of, gate_of, slot_of);

  // W1 [e][D][F] -> w1t [e][F][D]
  tconv_kernel<<<dim3(F_DIM / 64, D_DIM / 64, E_NUM), 256, 0, stream>>>(W1, wt, D_DIM, F_DIM);
  gemm1_kernel<<<8 * 16 * GROWS, NTH, 0, stream>>>(
      xb, wt, b1, off, cnt, tok_of, h);
  // W2 [e][F][D] -> w2t [e][D][F]
  tconv_kernel<<<dim3(D_DIM / 64, F_DIM / 64, E_NUM), 256, 0, stream>>>(W2, wt, F_DIM, D_DIM);
  gemm2_kernel<<<8 * KSPL * 4 * GROWS, NTH, 0, stream>>>(
      h, wt, b2, off, cnt, yp);
  combine_kernel<<<T_TOK, 256, 0, stream>>>(yp, slot_of, tgate, out);
}

// Round 15
// 417.392 us; speedup vs baseline: 1.1519x; 1.1519x over previous
//
#include <hip/hip_runtime.h>
#include <hip/hip_bf16.h>
#include <math.h>

typedef short short8 __attribute__((ext_vector_type(8)));
typedef short s4v __attribute__((ext_vector_type(4)));
typedef float f32x4 __attribute__((ext_vector_type(4)));
typedef unsigned short ushort4v __attribute__((ext_vector_type(4)));

#define T_TOK 4096
#define D_DIM 1024
#define E_NUM 8
#define F_DIM 4096
#define NSLOT (2 * T_TOK)

#define BM 128
#define BN 128
#define BK 32
#define GROWS 10    // row tiles of 128 (covers count <= 1280 ≈ mean + 8.5 sigma)
#define KSPL 3      // gemm2 split-K ways (43/43/42 K-tiles)

#define NCONV 8192          // 64x64 transpose tiles per weight tensor (E*16*64)
#define NROUTB (T_TOK / 4)  // router blocks (4 tokens per 256-thr block)
#define G1BLK (8 * 32 * GROWS)  // gemm1 blocks = 2560

__device__ __forceinline__ short f2bf(float f) {
  unsigned u = __builtin_bit_cast(unsigned, f);
  u = (u + 0x7FFFu + ((u >> 16) & 1u)) >> 16;
  return (short)u;
}
__device__ __forceinline__ float bf2f(unsigned short s) {
  unsigned u = ((unsigned)s) << 16;
  return __builtin_bit_cast(float, u);
}

__device__ __forceinline__ void gload_lds16(unsigned short* lds, const unsigned short* g) {
  __builtin_amdgcn_global_load_lds(
      (const __attribute__((address_space(1))) unsigned int*)g,
      (__attribute__((address_space(3))) unsigned int*)lds, 16, 0, 0);
}

#define MFMA_BF16 __builtin_amdgcn_mfma_f32_16x16x32_bf16
// swizzle: phys_slot = logical_slot ^ FSWZ(row); free 2-way
#define FSWZ(r) (((r) >> 1) & 3)

// ---------------- transpose-convert body: in [R][C] fp32 -> out [C][R] bf16, 64x64 tile ----------------
__device__ __forceinline__ void tconv_body(
    const float* __restrict__ ine, unsigned short* __restrict__ oute,
    int R, int C, int c0, int r0, float (*tile)[65]) {
  int tid = threadIdx.x;
  int lr = tid >> 4;
  int lc = (tid & 15) * 4;
#pragma unroll
  for (int p = 0; p < 4; ++p) {
    int row = p * 16 + lr;
    float4 v = *(const float4*)&ine[(size_t)(r0 + row) * C + c0 + lc];
    tile[row][lc] = v.x; tile[row][lc + 1] = v.y;
    tile[row][lc + 2] = v.z; tile[row][lc + 3] = v.w;
  }
  __syncthreads();
#pragma unroll
  for (int p = 0; p < 4; ++p) {
    int crow = p * 16 + lr;
    s4v o;
#pragma unroll
    for (int j = 0; j < 4; ++j) o[j] = f2bf(tile[lc + j][crow]);
    *(s4v*)&oute[(size_t)(c0 + crow) * R + r0 + lc] = o;
  }
}

// ---------------- Fused: tconv(W1) blocks + router blocks (4 tokens / 256-thr block) ----------------
__global__ __launch_bounds__(256) void pre_kernel(
    const float* __restrict__ x, const float* __restrict__ Wg,
    const float* __restrict__ bg, const float* __restrict__ W1,
    unsigned short* __restrict__ w1t,
    int* __restrict__ texp, float* __restrict__ tgate, int* __restrict__ cnt,
    unsigned short* __restrict__ xb) {
  __shared__ float tile[64][65];
  int bid = blockIdx.x;
  if (bid < NCONV) {
    // W1 [e][D][F] -> w1t [e][F][D]:  R=D_DIM, C=F_DIM
    int e = bid & 7;
    int q = bid >> 3;
    int c0 = (q & 63) * 64;      // over F (C/64 = 64)
    int r0 = (q >> 6) * 64;      // over D (R/64 = 16)
    tconv_body(W1 + (size_t)e * D_DIM * F_DIM, w1t + (size_t)e * D_DIM * F_DIM,
               D_DIM, F_DIM, c0, r0, tile);
    return;
  }
  int rb = bid - NCONV;
  int wid = threadIdx.x >> 6;
  int lane = threadIdx.x & 63;
  int t = rb * 4 + wid;

  double acc[E_NUM];
#pragma unroll
  for (int e = 0; e < E_NUM; ++e) acc[e] = 0.0;
  const float* xr = x + (size_t)t * D_DIM;
  unsigned short* xbr = xb + (size_t)t * D_DIM;
  for (int d = lane; d < D_DIM; d += 64) {
    float xf = xr[d];
    xbr[d] = (unsigned short)f2bf(xf);
    double xv = (double)xf;
#pragma unroll
    for (int e = 0; e < E_NUM; ++e) acc[e] += xv * (double)Wg[d * E_NUM + e];
  }
#pragma unroll
  for (int off = 32; off > 0; off >>= 1) {
#pragma unroll
    for (int e = 0; e < E_NUM; ++e) acc[e] += __shfl_down(acc[e], off);
  }
  if (lane == 0) {
    double lg[E_NUM];
    double m = -1e300;
#pragma unroll
    for (int e = 0; e < E_NUM; ++e) {
      lg[e] = acc[e] + (double)bg[e];
      m = fmax(m, lg[e]);
    }
    double s = 0.0;
#pragma unroll
    for (int e = 0; e < E_NUM; ++e) { lg[e] = exp(lg[e] - m); s += lg[e]; }
    int e0 = 0; double g0 = lg[0];
#pragma unroll
    for (int e = 1; e < E_NUM; ++e) if (lg[e] > g0) { g0 = lg[e]; e0 = e; }
    int e1 = -1; double g1 = -1.0;
#pragma unroll
    for (int e = 0; e < E_NUM; ++e)
      if (e != e0 && lg[e] > g1) { g1 = lg[e]; e1 = e; }
    texp[2 * t]     = e0;
    texp[2 * t + 1] = e1;
    tgate[2 * t]     = (float)(g0 / s);
    tgate[2 * t + 1] = (float)(g1 / s);
    atomicAdd(&cnt[e0], 1);
    atomicAdd(&cnt[e1], 1);
  }
}

__global__ void offsets_kernel(const int* __restrict__ cnt,
                               int* __restrict__ off, int* __restrict__ cur) {
  if (threadIdx.x == 0 && blockIdx.x == 0) {
    int o = 0;
    for (int e = 0; e < E_NUM; ++e) { off[e] = o; cur[e] = o; o += cnt[e]; }
    off[E_NUM] = o;
  }
}

__global__ __launch_bounds__(256) void assign_kernel(
    const int* __restrict__ texp, const float* __restrict__ tgate,
    int* __restrict__ cur, int* __restrict__ tok_of, float* __restrict__ gate_of,
    int* __restrict__ slot_of) {
  int t = blockIdx.x * 256 + threadIdx.x;
  if (t >= T_TOK) return;
#pragma unroll
  for (int k = 0; k < 2; ++k) {
    int e = texp[2 * t + k];
    int s = atomicAdd(&cur[e], 1);
    tok_of[s] = t;
    gate_of[s] = tgate[2 * t + k];
    slot_of[2 * t + k] = s;
  }
}

// ---------------- standalone tconv (fallback path for W2) ----------------
__global__ __launch_bounds__(256) void tconv_kernel(
    const float* __restrict__ in, unsigned short* __restrict__ out, int R, int C) {
  __shared__ float tile[64][65];
  int e = blockIdx.z;
  tconv_body(in + (size_t)e * R * C, out + (size_t)e * R * C,
             R, C, blockIdx.x * 64, blockIdx.y * 64, tile);
}

// ============ GEMM1 (R13-proven 128x128/BK32/256thr) fused with optional tconv(W2) blocks ============
// bid < gemm_blocks: gemm1, 1D XCD-pinned bid = e + 8*(fx + 32*ty)
// bid >= gemm_blocks: tconv W2 [e][F][D] -> w2dst [e][D][F]  (R=F, C=D)
__global__ __launch_bounds__(256, 4) void gemm1_kernel(
    const unsigned short* __restrict__ xb, const unsigned short* __restrict__ w1t,
    const float* __restrict__ b1,
    const int* __restrict__ off, const int* __restrict__ cnt,
    const int* __restrict__ tok_of, unsigned short* __restrict__ h,
    const float* __restrict__ W2src, unsigned short* __restrict__ w2dst,
    int gemm_blocks) {
  __shared__ __align__(16) char smem[4 * BM * BK * 2];   // 32 KB union
  int bid = blockIdx.x;
  if (bid >= gemm_blocks) {
    int tix = bid - gemm_blocks;
    int e = tix & 7;
    int q = tix >> 3;
    int c0 = (q & 15) * 64;      // over D (C/64 = 16)
    int r0 = (q >> 4) * 64;      // over F (R/64 = 64)
    float (*tile)[65] = reinterpret_cast<float(*)[65]>(smem);
    tconv_body(W2src + (size_t)e * F_DIM * D_DIM, w2dst + (size_t)e * F_DIM * D_DIM,
               F_DIM, D_DIM, c0, r0, tile);
    return;
  }
  unsigned short (*As)[BM * BK] = reinterpret_cast<unsigned short(*)[BM * BK]>(smem);
  unsigned short (*Bs)[BN * BK] = reinterpret_cast<unsigned short(*)[BN * BK]>(smem + 2 * BM * BK * 2);

  int e = bid & 7;
  int w = bid >> 3;
  int fx = w & 31;
  int ty = w >> 5;
  int count = cnt[e];
  if (ty * BM >= count) return;
  int f0 = fx * BN;
  int base = off[e] + ty * BM;

  int tid = threadIdx.x;
  int lane = tid & 63;
  int wid = tid >> 6;
  int wr = wid >> 1, wc = wid & 1;   // wave tile 64x64

  const unsigned short* aga[2];
  const unsigned short* bga[2];
  const unsigned short* w1e = w1t + (size_t)e * ((size_t)F_DIM * D_DIM);
#pragma unroll
  for (int i = 0; i < 2; ++i) {
    int pos = i * 256 + tid;
    int row = pos >> 2;
    int sl = (pos & 3) ^ FSWZ(row & 15);
    int idx = ty * BM + row;
    int tok = tok_of[(idx < count) ? (base + row) : off[e]];
    aga[i] = xb + (size_t)tok * D_DIM + sl * 8;
    bga[i] = w1e + (size_t)(f0 + row) * D_DIM + sl * 8;
  }

  f32x4 acc[4][4];
#pragma unroll
  for (int m = 0; m < 4; ++m)
#pragma unroll
    for (int n = 0; n < 4; ++n) acc[m][n] = (f32x4){0.f, 0.f, 0.f, 0.f};

#define STAGE1(buf, k0) do { \
    _Pragma("unroll") \
    for (int i = 0; i < 2; ++i) { \
      gload_lds16(&As[buf][(i * 256 + tid) * 8], aga[i] + (k0)); \
      gload_lds16(&Bs[buf][(i * 256 + tid) * 8], bga[i] + (k0)); \
    } \
  } while (0)

  STAGE1(0, 0);
  __syncthreads();

  int rr = lane & 15, hi = lane >> 4;
  int so = (hi ^ FSWZ(rr)) * 8;
  const int nt = D_DIM / BK;                   // 32
  for (int t = 0; t < nt; ++t) {
    int b = t & 1;
    if (t + 1 < nt) STAGE1(b ^ 1, (t + 1) * BK);
    const unsigned short* ab = &As[b][0];
    const unsigned short* bb = &Bs[b][0];
    short8 af[4], bf[4];
#pragma unroll
    for (int m = 0; m < 4; ++m)
      af[m] = *(const short8*)(ab + (wr * 64 + m * 16 + rr) * 32 + so);
#pragma unroll
    for (int n = 0; n < 4; ++n)
      bf[n] = *(const short8*)(bb + (wc * 64 + n * 16 + rr) * 32 + so);
    __builtin_amdgcn_s_setprio(1);
#pragma unroll
    for (int m = 0; m < 4; ++m)
#pragma unroll
      for (int n = 0; n < 4; ++n)
        acc[m][n] = MFMA_BF16(af[m], bf[n], acc[m][n], 0, 0, 0);
    __builtin_amdgcn_s_setprio(0);
    __syncthreads();
  }
#undef STAGE1

  int col = lane & 15, rowq = (lane >> 4) * 4;
  float bias[4];
#pragma unroll
  for (int n = 0; n < 4; ++n) bias[n] = b1[e * F_DIM + f0 + wc * 64 + n * 16 + col];
#pragma unroll
  for (int m = 0; m < 4; ++m)
#pragma unroll
    for (int i = 0; i < 4; ++i) {
      int rl = wr * 64 + m * 16 + rowq + i;
      if (ty * BM + rl < count) {
        int slot = base + rl;
#pragma unroll
        for (int n = 0; n < 4; ++n) {
          int f = f0 + wc * 64 + n * 16 + col;
          float v = acc[m][n][i] + bias[n];
          h[(size_t)slot * F_DIM + f] = (unsigned short)f2bf(fmaxf(v, 0.f));
        }
      }
    }
}

// ---------------- Grouped GEMM2 (split-K=3, contention-free): yp[kc][slot][D] bf16 ----------------
// 1D grid XCD-pinned: bid = e + 8*(kc + 3*(cx + 8*ty)); K-tiles per kc: 43/43/42
__global__ __launch_bounds__(256, 4) void gemm2_kernel(
    const unsigned short* __restrict__ h, const unsigned short* __restrict__ w2t,
    const float* __restrict__ b2,
    const int* __restrict__ off, const int* __restrict__ cnt,
    unsigned short* __restrict__ yp) {
  int bid = blockIdx.x;
  int e = bid & 7;
  int w = bid >> 3;
  int kc = w % 3;
  int u = w / 3;
  int cx = u & 7;
  int ty = u >> 3;
  int count = cnt[e];
  if (ty * BM >= count) return;
  int d0 = cx * BN;
  int klo = kc * 43 * BK;                   // 0, 1376, 2752
  const int nt = (kc < 2) ? 43 : 42;
  int base = off[e] + ty * BM;

  __shared__ __align__(16) unsigned short As[2][BM * BK];
  __shared__ __align__(16) unsigned short Bs[2][BN * BK];

  int tid = threadIdx.x;
  int lane = tid & 63;
  int wid = tid >> 6;
  int wr = wid >> 1, wc = wid & 1;

  const unsigned short* aga[2];
  const unsigned short* bga[2];
  const unsigned short* w2e = w2t + (size_t)e * ((size_t)D_DIM * F_DIM);
#pragma unroll
  for (int i = 0; i < 2; ++i) {
    int pos = i * 256 + tid;
    int row = pos >> 2;
    int sl = (pos & 3) ^ FSWZ(row & 15);
    int arow = base + row;
    if (arow > NSLOT - 1) arow = NSLOT - 1;
    aga[i] = h + (size_t)arow * F_DIM + klo + sl * 8;
    bga[i] = w2e + (size_t)(d0 + row) * F_DIM + klo + sl * 8;
  }

  f32x4 acc[4][4];
#pragma unroll
  for (int m = 0; m < 4; ++m)
#pragma unroll
    for (int n = 0; n < 4; ++n) acc[m][n] = (f32x4){0.f, 0.f, 0.f, 0.f};

#define STAGE2(buf, k0) do { \
    _Pragma("unroll") \
    for (int i = 0; i < 2; ++i) { \
      gload_lds16(&As[buf][(i * 256 + tid) * 8], aga[i] + (k0)); \
      gload_lds16(&Bs[buf][(i * 256 + tid) * 8], bga[i] + (k0)); \
    } \
  } while (0)

  STAGE2(0, 0);
  __syncthreads();

  int rr = lane & 15, hi = lane >> 4;
  int so = (hi ^ FSWZ(rr)) * 8;
  for (int t = 0; t < nt; ++t) {
    int b = t & 1;
    if (t + 1 < nt) STAGE2(b ^ 1, (t + 1) * BK);
    const unsigned short* ab = &As[b][0];
    const unsigned short* bb = &Bs[b][0];
    short8 af[4], bf[4];
#pragma unroll
    for (int m = 0; m < 4; ++m)
      af[m] = *(const short8*)(ab + (wr * 64 + m * 16 + rr) * 32 + so);
#pragma unroll
    for (int n = 0; n < 4; ++n)
      bf[n] = *(const short8*)(bb + (wc * 64 + n * 16 + rr) * 32 + so);
    __builtin_amdgcn_s_setprio(1);
#pragma unroll
    for (int m = 0; m < 4; ++m)
#pragma unroll
      for (int n = 0; n < 4; ++n)
        acc[m][n] = MFMA_BF16(af[m], bf[n], acc[m][n], 0, 0, 0);
    __builtin_amdgcn_s_setprio(0);
    __syncthreads();
  }
#undef STAGE2

  int col = lane & 15, rowq = (lane >> 4) * 4;
  float bias[4];
#pragma unroll
  for (int n = 0; n < 4; ++n)
    bias[n] = (kc == 0) ? b2[e * D_DIM + d0 + wc * 64 + n * 16 + col] : 0.f;
  unsigned short* ypk = yp + (size_t)kc * NSLOT * D_DIM;
#pragma unroll
  for (int m = 0; m < 4; ++m)
#pragma unroll
    for (int i = 0; i < 4; ++i) {
      int rl = wr * 64 + m * 16 + rowq + i;
      if (ty * BM + rl < count) {
        int slot = base + rl;
#pragma unroll
        for (int n = 0; n < 4; ++n) {
          int d = d0 + wc * 64 + n * 16 + col;
          float v = acc[m][n][i] + bias[n];
          ypk[(size_t)slot * D_DIM + d] = (unsigned short)f2bf(v);
        }
      }
    }
}

// ---------------- Combine: out[t] = sum_k gate_k * sum_kc yp[kc][slot_k] ----------------
__global__ __launch_bounds__(256) void combine_kernel(
    const unsigned short* __restrict__ yp, const int* __restrict__ slot_of,
    const float* __restrict__ tgate, float* __restrict__ out) {
  int t = blockIdx.x;
  int d = threadIdx.x * 4;
  int s0 = slot_of[2 * t], s1 = slot_of[2 * t + 1];
  float g0 = tgate[2 * t], g1 = tgate[2 * t + 1];
  float4 o = {0.f, 0.f, 0.f, 0.f};
  float* op = (float*)&o;
#pragma unroll
  for (int kc = 0; kc < KSPL; ++kc) {
    const unsigned short* ypk = yp + (size_t)kc * NSLOT * D_DIM;
    ushort4v a = *(const ushort4v*)&ypk[(size_t)s0 * D_DIM + d];
    ushort4v b = *(const ushort4v*)&ypk[(size_t)s1 * D_DIM + d];
#pragma unroll
    for (int j = 0; j < 4; ++j)
      op[j] += g0 * bf2f(a[j]) + g1 * bf2f(b[j]);
  }
  *(float4*)&out[(size_t)t * D_DIM + d] = o;
}

extern "C" void kernel_launch(void* const* d_in, const int* in_sizes, int n_in,
                              void* d_out, int out_size, void* d_ws, size_t ws_size,
                              hipStream_t stream) {
  const float* x  = (const float*)d_in[0];
  const float* Wg = (const float*)d_in[1];
  const float* bg = (const float*)d_in[2];
  const float* W1 = (const float*)d_in[3];
  const float* b1 = (const float*)d_in[4];
  const float* W2 = (const float*)d_in[5];
  const float* b2 = (const float*)d_in[6];
  float* out = (float*)d_out;

  char* ws = (char*)d_ws;
  int*   cnt     = (int*)(ws + 0);
  int*   cur     = (int*)(ws + 256);
  int*   off     = (int*)(ws + 512);
  int*   texp    = (int*)(ws + 1024);
  float* tgate   = (float*)(ws + 1024 + NSLOT * 4);
  int*   tok_of  = (int*)(ws + 1024 + NSLOT * 8);
  float* gate_of = (float*)(ws + 1024 + NSLOT * 12);
  int*   slot_of = (int*)(ws + 1024 + NSLOT * 16);

  const size_t WSZ  = (size_t)E_NUM * D_DIM * F_DIM * 2;   // 64 MB (one bf16 weight tensor)
  const size_t HSZ  = (size_t)NSLOT * F_DIM * 2;           // 64 MB
  const size_t YPSZ = (size_t)KSPL * NSLOT * D_DIM * 2;    // 48 MB
  size_t o_xb = 256 * 1024;
  size_t o_w1 = o_xb + (size_t)T_TOK * D_DIM * 2;          // +8 MB
  // overlap path needs a second weight buffer
  bool overlap = ws_size >= o_w1 + 2 * WSZ + HSZ + YPSZ;
  size_t o_w2 = overlap ? (o_w1 + WSZ) : o_w1;
  size_t o_h  = o_w2 + WSZ;
  size_t o_yp = o_h + HSZ;

  unsigned short* xb  = (unsigned short*)(ws + o_xb);
  unsigned short* w1t = (unsigned short*)(ws + o_w1);
  unsigned short* w2t = (unsigned short*)(ws + o_w2);
  unsigned short* h   = (unsigned short*)(ws + o_h);
  unsigned short* yp  = (unsigned short*)(ws + o_yp);

  hipMemsetAsync(ws, 0, 256, stream);

  // router (4 tok/block) + tconv W1, fused
  pre_kernel<<<NCONV + NROUTB, 256, 0, stream>>>(
      x, Wg, bg, W1, w1t, texp, tgate, cnt, xb);
  offsets_kernel<<<1, 64, 0, stream>>>(cnt, off, cur);
  assign_kernel<<<(T_TOK + 255) / 256, 256, 0, stream>>>(
      texp, tgate, cur, tok_of, gate_of, slot_of);

  if (overlap) {
    // gemm1 with tconv(W2) blocks fused in (independent buffers)
    gemm1_kernel<<<G1BLK + NCONV, 256, 0, stream>>>(
        xb, w1t, b1, off, cnt, tok_of, h, W2, w2t, G1BLK);
  } else {
    gemm1_kernel<<<G1BLK, 256, 0, stream>>>(
        xb, w1t, b1, off, cnt, tok_of, h, W2, w2t, G1BLK);
    // sequential W2 transpose into the (shared) weight buffer
    tconv_kernel<<<dim3(D_DIM / 64, F_DIM / 64, E_NUM), 256, 0, stream>>>(
        W2, w2t, F_DIM, D_DIM);
  }

  gemm2_kernel<<<8 * KSPL * 8 * GROWS, 256, 0, stream>>>(
      h, w2t, b2, off, cnt, yp);
  combine_kernel<<<T_TOK, 256, 0, stream>>>(yp, slot_of, tgate, out);
}

// Round 16
// 302.160 us; speedup vs baseline: 1.5911x; 1.3814x over previous
//
#include <hip/hip_runtime.h>
#include <hip/hip_bf16.h>
#include <math.h>

typedef short short8 __attribute__((ext_vector_type(8)));
typedef short s4v __attribute__((ext_vector_type(4)));
typedef float f32x4 __attribute__((ext_vector_type(4)));
typedef unsigned short ushort4v __attribute__((ext_vector_type(4)));

#define T_TOK 4096
#define D_DIM 1024
#define E_NUM 8
#define F_DIM 4096
#define NSLOT (2 * T_TOK)

#define BM 128
#define BN 128
#define BK 32
#define GROWS 10    // row tiles of 128 (covers count <= 1280 ≈ mean + 8.5 sigma)
#define KSPL 3      // gemm2 split-K ways (43/43/42 K-tiles)

#define NCONV 8192          // 64x64 transpose tiles per weight tensor
#define NROUTB (T_TOK / 4)  // router blocks (4 tokens per 256-thr block)
#define G1BLK (8 * 32 * GROWS)  // gemm1 blocks = 2560
#define NGRP 64             // token groups of 64 for ballot-scatter

__device__ __forceinline__ short f2bf(float f) {
  unsigned u = __builtin_bit_cast(unsigned, f);
  u = (u + 0x7FFFu + ((u >> 16) & 1u)) >> 16;
  return (short)u;
}
__device__ __forceinline__ float bf2f(unsigned short s) {
  unsigned u = ((unsigned)s) << 16;
  return __builtin_bit_cast(float, u);
}

__device__ __forceinline__ void gload_lds16(unsigned short* lds, const unsigned short* g) {
  __builtin_amdgcn_global_load_lds(
      (const __attribute__((address_space(1))) unsigned int*)g,
      (__attribute__((address_space(3))) unsigned int*)lds, 16, 0, 0);
}

#define MFMA_BF16 __builtin_amdgcn_mfma_f32_16x16x32_bf16
// swizzle: phys_slot = logical_slot ^ FSWZ(row); free 2-way
#define FSWZ(r) (((r) >> 1) & 3)

// ---------------- transpose-convert body: in [R][C] fp32 -> out [C][R] bf16, 64x64 tile ----------------
__device__ __forceinline__ void tconv_body(
    const float* __restrict__ ine, unsigned short* __restrict__ oute,
    int R, int C, int c0, int r0, float (*tile)[65]) {
  int tid = threadIdx.x;
  int lr = tid >> 4;
  int lc = (tid & 15) * 4;
#pragma unroll
  for (int p = 0; p < 4; ++p) {
    int row = p * 16 + lr;
    float4 v = *(const float4*)&ine[(size_t)(r0 + row) * C + c0 + lc];
    tile[row][lc] = v.x; tile[row][lc + 1] = v.y;
    tile[row][lc + 2] = v.z; tile[row][lc + 3] = v.w;
  }
  __syncthreads();
#pragma unroll
  for (int p = 0; p < 4; ++p) {
    int crow = p * 16 + lr;
    s4v o;
#pragma unroll
    for (int j = 0; j < 4; ++j) o[j] = f2bf(tile[lc + j][crow]);
    *(s4v*)&oute[(size_t)(c0 + crow) * R + r0 + lc] = o;
  }
}

// ---------------- Fused: tconv(W1) blocks + router blocks (NO atomics) ----------------
__global__ __launch_bounds__(256) void pre_kernel(
    const float* __restrict__ x, const float* __restrict__ Wg,
    const float* __restrict__ bg, const float* __restrict__ W1,
    unsigned short* __restrict__ w1t,
    int* __restrict__ texp, float* __restrict__ tgate,
    unsigned short* __restrict__ xb) {
  __shared__ float tile[64][65];
  int bid = blockIdx.x;
  if (bid < NCONV) {
    // W1 [e][D][F] -> w1t [e][F][D]:  R=D_DIM, C=F_DIM
    int e = bid & 7;
    int q = bid >> 3;
    int c0 = (q & 63) * 64;
    int r0 = (q >> 6) * 64;
    tconv_body(W1 + (size_t)e * D_DIM * F_DIM, w1t + (size_t)e * D_DIM * F_DIM,
               D_DIM, F_DIM, c0, r0, tile);
    return;
  }
  int rb = bid - NCONV;
  int wid = threadIdx.x >> 6;
  int lane = threadIdx.x & 63;
  int t = rb * 4 + wid;

  double acc[E_NUM];
#pragma unroll
  for (int e = 0; e < E_NUM; ++e) acc[e] = 0.0;
  const float* xr = x + (size_t)t * D_DIM;
  unsigned short* xbr = xb + (size_t)t * D_DIM;
  for (int d = lane; d < D_DIM; d += 64) {
    float xf = xr[d];
    xbr[d] = (unsigned short)f2bf(xf);
    double xv = (double)xf;
#pragma unroll
    for (int e = 0; e < E_NUM; ++e) acc[e] += xv * (double)Wg[d * E_NUM + e];
  }
#pragma unroll
  for (int off = 32; off > 0; off >>= 1) {
#pragma unroll
    for (int e = 0; e < E_NUM; ++e) acc[e] += __shfl_down(acc[e], off);
  }
  if (lane == 0) {
    double lg[E_NUM];
    double m = -1e300;
#pragma unroll
    for (int e = 0; e < E_NUM; ++e) {
      lg[e] = acc[e] + (double)bg[e];
      m = fmax(m, lg[e]);
    }
    double s = 0.0;
#pragma unroll
    for (int e = 0; e < E_NUM; ++e) { lg[e] = exp(lg[e] - m); s += lg[e]; }
    int e0 = 0; double g0 = lg[0];
#pragma unroll
    for (int e = 1; e < E_NUM; ++e) if (lg[e] > g0) { g0 = lg[e]; e0 = e; }
    int e1 = -1; double g1 = -1.0;
#pragma unroll
    for (int e = 0; e < E_NUM; ++e)
      if (e != e0 && lg[e] > g1) { g1 = lg[e]; e1 = e; }
    texp[2 * t]     = e0;
    texp[2 * t + 1] = e1;
    tgate[2 * t]     = (float)(g0 / s);
    tgate[2 * t + 1] = (float)(g1 / s);
  }
}

// ---------------- count: ballot-based per-group counts + in-group ranks (atomic-free) ----------------
__global__ __launch_bounds__(64) void count_kernel(
    const int* __restrict__ texp, int* __restrict__ grp_cnt, int* __restrict__ rank_of) {
  __shared__ int lcnt[E_NUM];
  int g = blockIdx.x;
  int lane = threadIdx.x;
  int t = g * 64 + lane;
  int e0 = texp[2 * t], e1 = texp[2 * t + 1];
  unsigned long long below = (1ULL << lane) - 1ULL;
  int r0 = 0, r1 = 0;
#pragma unroll
  for (int e = 0; e < E_NUM; ++e) {
    unsigned long long m0 = __ballot(e0 == e);
    unsigned long long m1 = __ballot(e1 == e);
    int c0 = __popcll(m0);
    if (e0 == e) r0 = __popcll(m0 & below);
    if (e1 == e) r1 = c0 + __popcll(m1 & below);
    if (lane == 0) lcnt[e] = c0 + __popcll(m1);
  }
  rank_of[2 * t]     = r0;
  rank_of[2 * t + 1] = r1;
  __syncthreads();
  if (lane < E_NUM) grp_cnt[g * E_NUM + lane] = lcnt[lane];
}

// ---------------- offsets: prefix-sum 64x8 -> off[], cnt[], base[g][e] ----------------
__global__ __launch_bounds__(64) void offsets_kernel(
    const int* __restrict__ grp_cnt, int* __restrict__ off,
    int* __restrict__ cnt, int* __restrict__ base) {
  __shared__ int tot[E_NUM], offs[E_NUM + 1];
  int lane = threadIdx.x;
  if (lane < E_NUM) {
    int s = 0;
    for (int g = 0; g < NGRP; ++g) s += grp_cnt[g * E_NUM + lane];
    tot[lane] = s;
  }
  __syncthreads();
  if (lane == 0) {
    int o = 0;
    for (int e = 0; e < E_NUM; ++e) { offs[e] = o; o += tot[e]; }
    offs[E_NUM] = o;
    for (int e = 0; e <= E_NUM; ++e) off[e] = offs[e];
    for (int e = 0; e < E_NUM; ++e) cnt[e] = tot[e];
  }
  __syncthreads();
  if (lane < E_NUM) {
    int run = offs[lane];
    for (int g = 0; g < NGRP; ++g) {
      base[g * E_NUM + lane] = run;
      run += grp_cnt[g * E_NUM + lane];
    }
  }
}

// ---------------- assign: pure stores (atomic-free, deterministic) ----------------
__global__ __launch_bounds__(256) void assign_kernel(
    const int* __restrict__ texp, const float* __restrict__ tgate,
    const int* __restrict__ base, const int* __restrict__ rank_of,
    int* __restrict__ tok_of, float* __restrict__ gate_of, int* __restrict__ slot_of) {
  int t = blockIdx.x * 256 + threadIdx.x;
  if (t >= T_TOK) return;
  int g = t >> 6;
#pragma unroll
  for (int k = 0; k < 2; ++k) {
    int e = texp[2 * t + k];
    int s = base[g * E_NUM + e] + rank_of[2 * t + k];
    tok_of[s] = t;
    gate_of[s] = tgate[2 * t + k];
    slot_of[2 * t + k] = s;
  }
}

// ---------------- standalone tconv (fallback path for W2) ----------------
__global__ __launch_bounds__(256) void tconv_kernel(
    const float* __restrict__ in, unsigned short* __restrict__ out, int R, int C) {
  __shared__ float tile[64][65];
  int e = blockIdx.z;
  tconv_body(in + (size_t)e * R * C, out + (size_t)e * R * C,
             R, C, blockIdx.x * 64, blockIdx.y * 64, tile);
}

// ============ GEMM1 (128x128/BK32/256thr) fused with optional tconv(W2) blocks ============
__global__ __launch_bounds__(256, 4) void gemm1_kernel(
    const unsigned short* __restrict__ xb, const unsigned short* __restrict__ w1t,
    const float* __restrict__ b1,
    const int* __restrict__ off, const int* __restrict__ cnt,
    const int* __restrict__ tok_of, unsigned short* __restrict__ h,
    const float* __restrict__ W2src, unsigned short* __restrict__ w2dst,
    int gemm_blocks) {
  __shared__ __align__(16) char smem[4 * BM * BK * 2];   // 32 KB union
  int bid = blockIdx.x;
  if (bid >= gemm_blocks) {
    int tix = bid - gemm_blocks;
    int e = tix & 7;
    int q = tix >> 3;
    int c0 = (q & 15) * 64;
    int r0 = (q >> 4) * 64;
    float (*tile)[65] = reinterpret_cast<float(*)[65]>(smem);
    tconv_body(W2src + (size_t)e * F_DIM * D_DIM, w2dst + (size_t)e * F_DIM * D_DIM,
               F_DIM, D_DIM, c0, r0, tile);
    return;
  }
  unsigned short (*As)[BM * BK] = reinterpret_cast<unsigned short(*)[BM * BK]>(smem);
  unsigned short (*Bs)[BN * BK] = reinterpret_cast<unsigned short(*)[BN * BK]>(smem + 2 * BM * BK * 2);

  int e = bid & 7;
  int w = bid >> 3;
  int fx = w & 31;
  int ty = w >> 5;
  int count = cnt[e];
  if (ty * BM >= count) return;
  int f0 = fx * BN;
  int base = off[e] + ty * BM;

  int tid = threadIdx.x;
  int lane = tid & 63;
  int wid = tid >> 6;
  int wr = wid >> 1, wc = wid & 1;

  const unsigned short* aga[2];
  const unsigned short* bga[2];
  const unsigned short* w1e = w1t + (size_t)e * ((size_t)F_DIM * D_DIM);
#pragma unroll
  for (int i = 0; i < 2; ++i) {
    int pos = i * 256 + tid;
    int row = pos >> 2;
    int sl = (pos & 3) ^ FSWZ(row & 15);
    int idx = ty * BM + row;
    int tok = tok_of[(idx < count) ? (base + row) : off[e]];
    aga[i] = xb + (size_t)tok * D_DIM + sl * 8;
    bga[i] = w1e + (size_t)(f0 + row) * D_DIM + sl * 8;
  }

  f32x4 acc[4][4];
#pragma unroll
  for (int m = 0; m < 4; ++m)
#pragma unroll
    for (int n = 0; n < 4; ++n) acc[m][n] = (f32x4){0.f, 0.f, 0.f, 0.f};

#define STAGE1(buf, k0) do { \
    _Pragma("unroll") \
    for (int i = 0; i < 2; ++i) { \
      gload_lds16(&As[buf][(i * 256 + tid) * 8], aga[i] + (k0)); \
      gload_lds16(&Bs[buf][(i * 256 + tid) * 8], bga[i] + (k0)); \
    } \
  } while (0)

  STAGE1(0, 0);
  __syncthreads();

  int rr = lane & 15, hi = lane >> 4;
  int so = (hi ^ FSWZ(rr)) * 8;
  const int nt = D_DIM / BK;                   // 32
  for (int t = 0; t < nt; ++t) {
    int b = t & 1;
    if (t + 1 < nt) STAGE1(b ^ 1, (t + 1) * BK);
    const unsigned short* ab = &As[b][0];
    const unsigned short* bb = &Bs[b][0];
    short8 af[4], bf[4];
#pragma unroll
    for (int m = 0; m < 4; ++m)
      af[m] = *(const short8*)(ab + (wr * 64 + m * 16 + rr) * 32 + so);
#pragma unroll
    for (int n = 0; n < 4; ++n)
      bf[n] = *(const short8*)(bb + (wc * 64 + n * 16 + rr) * 32 + so);
    __builtin_amdgcn_s_setprio(1);
#pragma unroll
    for (int m = 0; m < 4; ++m)
#pragma unroll
      for (int n = 0; n < 4; ++n)
        acc[m][n] = MFMA_BF16(af[m], bf[n], acc[m][n], 0, 0, 0);
    __builtin_amdgcn_s_setprio(0);
    __syncthreads();
  }
#undef STAGE1

  int col = lane & 15, rowq = (lane >> 4) * 4;
  float bias[4];
#pragma unroll
  for (int n = 0; n < 4; ++n) bias[n] = b1[e * F_DIM + f0 + wc * 64 + n * 16 + col];
#pragma unroll
  for (int m = 0; m < 4; ++m)
#pragma unroll
    for (int i = 0; i < 4; ++i) {
      int rl = wr * 64 + m * 16 + rowq + i;
      if (ty * BM + rl < count) {
        int slot = base + rl;
#pragma unroll
        for (int n = 0; n < 4; ++n) {
          int f = f0 + wc * 64 + n * 16 + col;
          float v = acc[m][n][i] + bias[n];
          h[(size_t)slot * F_DIM + f] = (unsigned short)f2bf(fmaxf(v, 0.f));
        }
      }
    }
}

// ---------------- Grouped GEMM2 (split-K=3, contention-free): yp[kc][slot][D] bf16 ----------------
__global__ __launch_bounds__(256, 4) void gemm2_kernel(
    const unsigned short* __restrict__ h, const unsigned short* __restrict__ w2t,
    const float* __restrict__ b2,
    const int* __restrict__ off, const int* __restrict__ cnt,
    unsigned short* __restrict__ yp) {
  int bid = blockIdx.x;
  int e = bid & 7;
  int w = bid >> 3;
  int kc = w % 3;
  int u = w / 3;
  int cx = u & 7;
  int ty = u >> 3;
  int count = cnt[e];
  if (ty * BM >= count) return;
  int d0 = cx * BN;
  int klo = kc * 43 * BK;
  const int nt = (kc < 2) ? 43 : 42;
  int base = off[e] + ty * BM;

  __shared__ __align__(16) unsigned short As[2][BM * BK];
  __shared__ __align__(16) unsigned short Bs[2][BN * BK];

  int tid = threadIdx.x;
  int lane = tid & 63;
  int wid = tid >> 6;
  int wr = wid >> 1, wc = wid & 1;

  const unsigned short* aga[2];
  const unsigned short* bga[2];
  const unsigned short* w2e = w2t + (size_t)e * ((size_t)D_DIM * F_DIM);
#pragma unroll
  for (int i = 0; i < 2; ++i) {
    int pos = i * 256 + tid;
    int row = pos >> 2;
    int sl = (pos & 3) ^ FSWZ(row & 15);
    int arow = base + row;
    if (arow > NSLOT - 1) arow = NSLOT - 1;
    aga[i] = h + (size_t)arow * F_DIM + klo + sl * 8;
    bga[i] = w2e + (size_t)(d0 + row) * F_DIM + klo + sl * 8;
  }

  f32x4 acc[4][4];
#pragma unroll
  for (int m = 0; m < 4; ++m)
#pragma unroll
    for (int n = 0; n < 4; ++n) acc[m][n] = (f32x4){0.f, 0.f, 0.f, 0.f};

#define STAGE2(buf, k0) do { \
    _Pragma("unroll") \
    for (int i = 0; i < 2; ++i) { \
      gload_lds16(&As[buf][(i * 256 + tid) * 8], aga[i] + (k0)); \
      gload_lds16(&Bs[buf][(i * 256 + tid) * 8], bga[i] + (k0)); \
    } \
  } while (0)

  STAGE2(0, 0);
  __syncthreads();

  int rr = lane & 15, hi = lane >> 4;
  int so = (hi ^ FSWZ(rr)) * 8;
  for (int t = 0; t < nt; ++t) {
    int b = t & 1;
    if (t + 1 < nt) STAGE2(b ^ 1, (t + 1) * BK);
    const unsigned short* ab = &As[b][0];
    const unsigned short* bb = &Bs[b][0];
    short8 af[4], bf[4];
#pragma unroll
    for (int m = 0; m < 4; ++m)
      af[m] = *(const short8*)(ab + (wr * 64 + m * 16 + rr) * 32 + so);
#pragma unroll
    for (int n = 0; n < 4; ++n)
      bf[n] = *(const short8*)(bb + (wc * 64 + n * 16 + rr) * 32 + so);
    __builtin_amdgcn_s_setprio(1);
#pragma unroll
    for (int m = 0; m < 4; ++m)
#pragma unroll
      for (int n = 0; n < 4; ++n)
        acc[m][n] = MFMA_BF16(af[m], bf[n], acc[m][n], 0, 0, 0);
    __builtin_amdgcn_s_setprio(0);
    __syncthreads();
  }
#undef STAGE2

  int col = lane & 15, rowq = (lane >> 4) * 4;
  float bias[4];
#pragma unroll
  for (int n = 0; n < 4; ++n)
    bias[n] = (kc == 0) ? b2[e * D_DIM + d0 + wc * 64 + n * 16 + col] : 0.f;
  unsigned short* ypk = yp + (size_t)kc * NSLOT * D_DIM;
#pragma unroll
  for (int m = 0; m < 4; ++m)
#pragma unroll
    for (int i = 0; i < 4; ++i) {
      int rl = wr * 64 + m * 16 + rowq + i;
      if (ty * BM + rl < count) {
        int slot = base + rl;
#pragma unroll
        for (int n = 0; n < 4; ++n) {
          int d = d0 + wc * 64 + n * 16 + col;
          float v = acc[m][n][i] + bias[n];
          ypk[(size_t)slot * D_DIM + d] = (unsigned short)f2bf(v);
        }
      }
    }
}

// ---------------- Combine ----------------
__global__ __launch_bounds__(256) void combine_kernel(
    const unsigned short* __restrict__ yp, const int* __restrict__ slot_of,
    const float* __restrict__ tgate, float* __restrict__ out) {
  int t = blockIdx.x;
  int d = threadIdx.x * 4;
  int s0 = slot_of[2 * t], s1 = slot_of[2 * t + 1];
  float g0 = tgate[2 * t], g1 = tgate[2 * t + 1];
  float4 o = {0.f, 0.f, 0.f, 0.f};
  float* op = (float*)&o;
#pragma unroll
  for (int kc = 0; kc < KSPL; ++kc) {
    const unsigned short* ypk = yp + (size_t)kc * NSLOT * D_DIM;
    ushort4v a = *(const ushort4v*)&ypk[(size_t)s0 * D_DIM + d];
    ushort4v b = *(const ushort4v*)&ypk[(size_t)s1 * D_DIM + d];
#pragma unroll
    for (int j = 0; j < 4; ++j)
      op[j] += g0 * bf2f(a[j]) + g1 * bf2f(b[j]);
  }
  *(float4*)&out[(size_t)t * D_DIM + d] = o;
}

extern "C" void kernel_launch(void* const* d_in, const int* in_sizes, int n_in,
                              void* d_out, int out_size, void* d_ws, size_t ws_size,
                              hipStream_t stream) {
  const float* x  = (const float*)d_in[0];
  const float* Wg = (const float*)d_in[1];
  const float* bg = (const float*)d_in[2];
  const float* W1 = (const float*)d_in[3];
  const float* b1 = (const float*)d_in[4];
  const float* W2 = (const float*)d_in[5];
  const float* b2 = (const float*)d_in[6];
  float* out = (float*)d_out;

  char* ws = (char*)d_ws;
  int*   off     = (int*)(ws + 0);                 // 9 ints
  int*   cnt     = (int*)(ws + 128);               // 8 ints
  int*   grp_cnt = (int*)(ws + 1024);              // 64*8 = 2 KB
  int*   base    = (int*)(ws + 4096);              // 2 KB
  int*   texp    = (int*)(ws + 8192);              // 32 KB
  float* tgate   = (float*)(ws + 8192 + NSLOT * 4);
  int*   rank_of = (int*)(ws + 8192 + NSLOT * 8);
  int*   tok_of  = (int*)(ws + 8192 + NSLOT * 12);
  float* gate_of = (float*)(ws + 8192 + NSLOT * 16);
  int*   slot_of = (int*)(ws + 8192 + NSLOT * 20);

  const size_t WSZ  = (size_t)E_NUM * D_DIM * F_DIM * 2;   // 64 MB
  const size_t HSZ  = (size_t)NSLOT * F_DIM * 2;           // 64 MB
  const size_t YPSZ = (size_t)KSPL * NSLOT * D_DIM * 2;    // 48 MB
  size_t o_xb = 256 * 1024;
  size_t o_w1 = o_xb + (size_t)T_TOK * D_DIM * 2;          // +8 MB
  bool overlap = ws_size >= o_w1 + 2 * WSZ + HSZ + YPSZ;
  size_t o_w2 = overlap ? (o_w1 + WSZ) : o_w1;
  size_t o_h  = o_w2 + WSZ;
  size_t o_yp = o_h + HSZ;

  unsigned short* xb  = (unsigned short*)(ws + o_xb);
  unsigned short* w1t = (unsigned short*)(ws + o_w1);
  unsigned short* w2t = (unsigned short*)(ws + o_w2);
  unsigned short* h   = (unsigned short*)(ws + o_h);
  unsigned short* yp  = (unsigned short*)(ws + o_yp);

  // router (no atomics) + tconv W1, fused
  pre_kernel<<<NCONV + NROUTB, 256, 0, stream>>>(
      x, Wg, bg, W1, w1t, texp, tgate, xb);
  count_kernel<<<NGRP, 64, 0, stream>>>(texp, grp_cnt, rank_of);
  offsets_kernel<<<1, 64, 0, stream>>>(grp_cnt, off, cnt, base);
  assign_kernel<<<(T_TOK + 255) / 256, 256, 0, stream>>>(
      texp, tgate, base, rank_of, tok_of, gate_of, slot_of);

  if (overlap) {
    gemm1_kernel<<<G1BLK + NCONV, 256, 0, stream>>>(
        xb, w1t, b1, off, cnt, tok_of, h, W2, w2t, G1BLK);
  } else {
    gemm1_kernel<<<G1BLK, 256, 0, stream>>>(
        xb, w1t, b1, off, cnt, tok_of, h, W2, w2t, G1BLK);
    tconv_kernel<<<dim3(D_DIM / 64, F_DIM / 64, E_NUM), 256, 0, stream>>>(
        W2, w2t, F_DIM, D_DIM);
  }

  gemm2_kernel<<<8 * KSPL * 8 * GROWS, 256, 0, stream>>>(
      h, w2t, b2, off, cnt, yp);
  combine_kernel<<<T_TOK, 256, 0, stream>>>(yp, slot_of, tgate, out);
}